// Round 9
// baseline (299.150 us; speedup 1.0000x reference)
//
#include <hip/hip_runtime.h>

// ---------------------------------------------------------------------------
// QalbAttention. B=2, N=2048, D=1024, H=16, HD=64.
// R5: attn 32x32x16 swapped-operand MFMA, lane-local softmax (81us).
// R7/R8: split-K attn refuted (spill 121us; no-spill 90.5us - merge overhead
//        beats latency gain). Atomic-free cvt partials: non-attn 227->181us.
// R9: attn back to R5 structure + s_setprio around MFMA (T5) + defer-max
//     rescale skip (T13). rope_table+scale_finalize merged into prep_kernel.
// ---------------------------------------------------------------------------

typedef short short8 __attribute__((ext_vector_type(8)));      // 8 bf16 (4 VGPR)
typedef float floatx4 __attribute__((ext_vector_type(4)));
typedef float f32x16 __attribute__((ext_vector_type(16)));
typedef unsigned int uint4v __attribute__((ext_vector_type(4)));
typedef unsigned int u32x4v __attribute__((ext_vector_type(4)));
typedef unsigned short us4 __attribute__((ext_vector_type(4)));
typedef unsigned short u16;

#define DEV __device__ __forceinline__

static const int Bb = 2;

// ws layout (bytes)
static const size_t OFF_XB = 0;                       // x bf16 8MB; dead after gemm_qkv -> V^T
static const size_t OFF_WQ = 8388608;
static const size_t OFF_WK = OFF_WQ + 2097152;
static const size_t OFF_WV = OFF_WK + 2097152;
static const size_t OFF_WO = OFF_WV + 2097152;
static const size_t OFF_Q  = OFF_WO + 2097152;        // (B,H,N,HD) bf16 8MB
static const size_t OFF_K  = OFF_Q + 8388608;
static const size_t OFF_V  = OFF_K + 8388608;
static const size_t OFF_AO = OFF_V + 8388608;         // attn-out 8MB; holds rope table BEFORE attn
static const size_t OFF_SC = OFF_AO + 8388608;        // [0:2) inv_scale; +16: 4096 partials (16KB)

DEV u16 f2bf(float f) {                               // RNE float->bf16
  unsigned int u = __builtin_bit_cast(unsigned int, f);
  u += 0x7fffu + ((u >> 16) & 1u);
  return (u16)(u >> 16);
}

DEV unsigned pkbf(float lo, float hi) {               // pack 2xf32 -> 2xbf16 (RNE)
  unsigned r;
  asm("v_cvt_pk_bf16_f32 %0, %1, %2" : "=v"(r) : "v"(lo), "v"(hi));
  return r;
}

// ---------------- fused fp32->bf16 convert + complexity dot ------------------
// blocks [0,4096): x (+ x.cw partial, atomic-free); [4096,8192): weights.
__global__ __launch_bounds__(256) void cvt_all_kernel(
    const float* __restrict__ x, const float* __restrict__ wq,
    const float* __restrict__ wk, const float* __restrict__ wv,
    const float* __restrict__ wo, const float* __restrict__ cw,
    u16* __restrict__ xb, u16* __restrict__ wqb, u16* __restrict__ wkb,
    u16* __restrict__ wvb, u16* __restrict__ wob, float* __restrict__ part) {
  const int blk = blockIdx.x;
  if (blk < 4096) {
    int i = blk * 256 + threadIdx.x;          // float4 index into x (1048576)
    float4 f = ((const float4*)x)[i];
    us4 o;
    o[0] = f2bf(f.x); o[1] = f2bf(f.y); o[2] = f2bf(f.z); o[3] = f2bf(f.w);
    ((us4*)xb)[i] = o;
    float4 c = ((const float4*)cw)[i & 255];  // D/4 = 256
    float acc = f.x * c.x + f.y * c.y + f.z * c.z + f.w * c.w;
    __shared__ float red[256];
    red[threadIdx.x] = acc;
    __syncthreads();
    for (int s = 128; s > 0; s >>= 1) {
      if (threadIdx.x < s) red[threadIdx.x] += red[threadIdx.x + s];
      __syncthreads();
    }
    if (threadIdx.x == 0) part[blk] = red[0];   // plain store, no atomics
  } else {
    int r = blk - 4096;
    int wi = r >> 10;
    int i = (r & 1023) * 256 + threadIdx.x;   // float4 index (262144)
    const float* src = (wi == 0) ? wq : (wi == 1) ? wk : (wi == 2) ? wv : wo;
    u16* dst = (wi == 0) ? wqb : (wi == 1) ? wkb : (wi == 2) ? wvb : wob;
    float4 f = ((const float4*)src)[i];
    us4 o;
    o[0] = f2bf(f.x); o[1] = f2bf(f.y); o[2] = f2bf(f.z); o[3] = f2bf(f.w);
    ((us4*)dst)[i] = o;
  }
}

// ---------------- prep: rope table (blocks 0..255) + scale finalize (256) ----
__global__ void prep_kernel(const float* __restrict__ part,
                            const float* __restrict__ cb,
                            const float* __restrict__ alpha,
                            const float* __restrict__ tb,
                            const int* __restrict__ tstep,
                            float* __restrict__ out, float2* __restrict__ rt) {
  if (blockIdx.x == 256) {
    const int b = threadIdx.x >> 7, t = threadIdx.x & 127;
    float s = 0.f;
    for (int i = t; i < 2048; i += 128) s += part[b * 2048 + i];
    __shared__ float red[2][128];
    red[b][t] = s;
    __syncthreads();
    for (int st = 64; st > 0; st >>= 1) {
      if (t < st) red[b][t] += red[b][t + st];
      __syncthreads();
    }
    if (t == 0) {
      float sm = red[b][0] * (1.0f / 2048.0f) + cb[0];
      float cx = 1.0f / (1.0f + expf(-sm));
      float Te = (fabsf(tb[0]) + 1.0f) * (0.5f + cx);
      float psi = 1.0f + alpha[0] * sinf(6.283185307179586f * (float)tstep[0] / Te);
      out[b] = 1.0f / (8.0f * psi);
    }
  } else {
    int i = blockIdx.x * 256 + threadIdx.x;   // 65536
    int pos = i >> 5, hd2 = i & 31;
    float ang = (float)pos * exp2f(-(float)hd2 * 0.41524101186092030f);
    float sv, cv;
    sincosf(ang, &sv, &cv);
    rt[i] = make_float2(cv, sv);
  }
}

// --------------------------- QKV GEMM + RoPE --------------------------------
__global__ __launch_bounds__(256) void gemm_qkv_kernel(
    const u16* __restrict__ xb, const u16* __restrict__ wq, const u16* __restrict__ wk,
    const u16* __restrict__ wv, const float2* __restrict__ rt,
    u16* __restrict__ q, u16* __restrict__ k, u16* __restrict__ v) {
  const int tm = blockIdx.x, tn = blockIdx.y, which = blockIdx.z;
  const u16* W = (which == 0) ? wq : (which == 1) ? wk : wv;
  u16* dst = (which == 0) ? q : (which == 1) ? k : v;

  __shared__ __align__(16) u16 As[128 * 32];
  __shared__ __align__(16) u16 Bs[128 * 32];

  const int t = threadIdx.x, lane = t & 63, w = t >> 6;
  const int wm = w >> 1, wn = w & 1, lg = lane >> 4, lr = lane & 15;

  floatx4 acc[4][4];
#pragma unroll
  for (int i = 0; i < 4; i++)
#pragma unroll
    for (int j = 0; j < 4; j++) acc[i][j] = (floatx4){0.f, 0.f, 0.f, 0.f};

  const int rowA = tm * 128, rowB = tn * 128;
  for (int kt = 0; kt < 32; ++kt) {
#pragma unroll
    for (int s = 0; s < 2; s++) {
      int c = t + s * 256;
      int r = c >> 2, kc = c & 3;
      *(uint4v*)(As + r * 32 + kc * 8) =
          *(const uint4v*)(xb + (size_t)(rowA + r) * 1024 + kt * 32 + kc * 8);
      *(uint4v*)(Bs + r * 32 + kc * 8) =
          *(const uint4v*)(W + (size_t)(rowB + r) * 1024 + kt * 32 + kc * 8);
    }
    __syncthreads();
    short8 af[4], bw[4];
#pragma unroll
    for (int i = 0; i < 4; i++)
      af[i] = *(const short8*)(As + (wm * 64 + i * 16 + lr) * 32 + lg * 8);
#pragma unroll
    for (int j = 0; j < 4; j++)
      bw[j] = *(const short8*)(Bs + (wn * 64 + j * 16 + lr) * 32 + lg * 8);
#pragma unroll
    for (int i = 0; i < 4; i++)
#pragma unroll
      for (int j = 0; j < 4; j++)
        acc[i][j] = __builtin_amdgcn_mfma_f32_16x16x32_bf16(af[i], bw[j], acc[i][j], 0, 0, 0);
    __syncthreads();
  }

  const int rowbase = tm * 128 + wm * 64, colbase = tn * 128 + wn * 64;
  if (which <= 1) {
#pragma unroll
    for (int i = 0; i < 4; i++)
#pragma unroll
      for (int ii = 0; ii < 4; ii++) {
        int gm = rowbase + i * 16 + lg * 4 + ii;
        int pos = gm & 2047, bb = gm >> 11;
#pragma unroll
        for (int jp = 0; jp < 2; jp++) {
          int hd2 = jp * 16 + lr;
          float2 cs = rt[pos * 32 + hd2];
          float a0 = acc[i][jp][ii], a1 = acc[i][jp + 2][ii];
          int e0 = colbase + jp * 16 + lr;
          int hh = e0 >> 6;
          size_t base = (((size_t)bb * 16 + hh) * 2048 + pos) * 64;
          dst[base + hd2]      = f2bf(a0 * cs.x - a1 * cs.y);
          dst[base + hd2 + 32] = f2bf(a1 * cs.x + a0 * cs.y);
        }
      }
  } else {
#pragma unroll
    for (int i = 0; i < 4; i++)
#pragma unroll
      for (int ii = 0; ii < 4; ii++) {
        int gm = rowbase + i * 16 + lg * 4 + ii;
        int pos = gm & 2047, bb = gm >> 11;
#pragma unroll
        for (int j = 0; j < 4; j++) {
          int ge = colbase + j * 16 + lr;
          int hh = ge >> 6, hd = ge & 63;
          dst[(((size_t)bb * 16 + hh) * 2048 + pos) * 64 + hd] = f2bf(acc[i][j][ii]);
        }
      }
  }
}

// --------------------------- V transpose ------------------------------------
__global__ __launch_bounds__(256) void vtrans_kernel(const u16* __restrict__ v,
                                                     u16* __restrict__ vt) {
  const int bh = blockIdx.x, nt = blockIdx.y;     // 32 x 32
  __shared__ __align__(16) u16 T[64 * 64];
  const int t = threadIdx.x;
  const size_t vi = (size_t)bh * 131072 + (size_t)nt * 4096;
#pragma unroll
  for (int s = 0; s < 2; s++) {
    int g = s * 256 + t, n = g >> 3, dc = g & 7;
    *(uint4v*)(T + n * 64 + ((dc ^ (n & 7)) * 8)) =
        *(const uint4v*)(v + vi + (size_t)n * 64 + dc * 8);
  }
  __syncthreads();
  const size_t vo = (size_t)bh * 131072 + (size_t)nt * 64;
#pragma unroll
  for (int s = 0; s < 2; s++) {
    int g = s * 256 + t, nc = g & 7, d = g >> 3;
    short8 o;
#pragma unroll
    for (int jj = 0; jj < 8; jj++) {
      int n = nc * 8 + jj;
      o[jj] = (short)T[n * 64 + (((d >> 3) ^ (n & 7)) * 8) + (d & 7)];
    }
    *(short8*)(vt + vo + (size_t)d * 2048 + nc * 8) = o;
  }
}

// --------------------------- flash attention (R5 + T5/T13) ------------------
// 512 blocks x 4 waves; wave owns a 32-row q-tile ({p,31-p,32+p,63-p} per
// block). S^T = mfma32x32(K,Q), lane-local softmax, in-register P, O^T.
// Riders: s_setprio around MFMA clusters; defer-max rescale skip (THR=8).
__global__ __launch_bounds__(256) void attn_kernel(
    const u16* __restrict__ q, const u16* __restrict__ k, const u16* __restrict__ vt,
    u16* __restrict__ ao, const float* __restrict__ scale_ws) {
  const int bid = blockIdx.x;
  const int swz = (bid & 7) * 64 + (bid >> 3);    // XCD x -> bh in [4x,4x+4)
  const int bh = swz >> 4, p = swz & 15;
  const int b = bh >> 4, h = bh & 15;
  const int w = threadIdx.x >> 6, lane = threadIdx.x & 63;
  const int l31 = lane & 31, hi = lane >> 5;
  const int tsel = (w == 0) ? p : (w == 1) ? 31 - p : (w == 2) ? 32 + p : 63 - p;
  const int q0 = tsel * 32;
  const int KT = tsel >> 1;
  const float isc2 = scale_ws[b] * 1.4426950408889634f;
  const size_t koff = (size_t)bh * 131072;
  const float NINF = -__builtin_inff();

  short8 bq[4];
#pragma unroll
  for (int k4 = 0; k4 < 4; k4++)
    bq[k4] = *(const short8*)(q + koff + (size_t)(q0 + l31) * 64 + k4 * 16 + hi * 8);

  f32x16 o0, o1;
#pragma unroll
  for (int r = 0; r < 16; r++) { o0[r] = 0.f; o1[r] = 0.f; }
  float m2 = NINF, ell = 0.f;

  for (int kt = 0; kt <= KT; ++kt) {
    const int cbase = kt << 6;
    const bool haveMt1 = (cbase + 32 <= q0 + 31);

    short8 ka0[4], ka1[4];
#pragma unroll
    for (int k4 = 0; k4 < 4; k4++)
      ka0[k4] = *(const short8*)(k + koff + (size_t)(cbase + l31) * 64 + k4 * 16 + hi * 8);
    if (haveMt1) {
#pragma unroll
      for (int k4 = 0; k4 < 4; k4++)
        ka1[k4] = *(const short8*)(k + koff + (size_t)(cbase + 32 + l31) * 64 + k4 * 16 + hi * 8);
    }
    const int nct = haveMt1 ? 4 : 2;
    short8 va0[4], va1[4];
#pragma unroll
    for (int ct = 0; ct < 4; ct++) {
      if (ct < nct) {
        va0[ct] = *(const short8*)(vt + koff + (size_t)l31 * 2048 + cbase + ct * 16 + hi * 8);
        va1[ct] = *(const short8*)(vt + koff + (size_t)(32 + l31) * 2048 + cbase + ct * 16 + hi * 8);
      }
    }

    f32x16 s0, s1;
#pragma unroll
    for (int r = 0; r < 16; r++) { s0[r] = 0.f; s1[r] = 0.f; }
    __builtin_amdgcn_s_setprio(1);
#pragma unroll
    for (int k4 = 0; k4 < 4; k4++)
      s0 = __builtin_amdgcn_mfma_f32_32x32x16_bf16(ka0[k4], bq[k4], s0, 0, 0, 0);
    if (haveMt1) {
#pragma unroll
      for (int k4 = 0; k4 < 4; k4++)
        s1 = __builtin_amdgcn_mfma_f32_32x32x16_bf16(ka1[k4], bq[k4], s1, 0, 0, 0);
    }
    __builtin_amdgcn_s_setprio(0);

#pragma unroll
    for (int r = 0; r < 16; r++) { s0[r] *= isc2; s1[r] *= isc2; }
    if (kt == KT) {
      const int thr = q0 + l31 - cbase;
#pragma unroll
      for (int r = 0; r < 16; r++) {
        const int crow = (r & 3) + 8 * (r >> 2) + 4 * hi;
        if (crow > thr) s0[r] = NINF;
        if (crow + 32 > thr) s1[r] = NINF;
      }
    }

    // online softmax with defer-max (T13): skip rescale while max growth <= 8
    float mx = s0[0];
#pragma unroll
    for (int r = 1; r < 16; r++) mx = fmaxf(mx, s0[r]);
#pragma unroll
    for (int r = 0; r < 16; r++) mx = fmaxf(mx, s1[r]);
    mx = fmaxf(mx, __shfl_xor(mx, 32, 64));
    if (!__all(mx <= m2 + 8.0f)) {
      const float mn = fmaxf(m2, mx);
      const float rsc = exp2f(m2 - mn);
      m2 = mn;
      ell *= rsc;
#pragma unroll
      for (int r = 0; r < 16; r++) { o0[r] *= rsc; o1[r] *= rsc; }
    }
    f32x16 p0, p1;
    float ps = 0.f;
#pragma unroll
    for (int r = 0; r < 16; r++) { p0[r] = exp2f(s0[r] - m2); ps += p0[r]; }
#pragma unroll
    for (int r = 0; r < 16; r++) { p1[r] = exp2f(s1[r] - m2); ps += p1[r]; }
    ps += __shfl_xor(ps, 32, 64);
    ell += ps;

    __builtin_amdgcn_s_setprio(1);
#pragma unroll
    for (int ct = 0; ct < 4; ct++) {
      if (ct < nct) {
        const f32x16& pp = (ct < 2) ? p0 : p1;
        const int rA = (ct & 1) * 8;
        unsigned pkA0 = pkbf(pp[rA + 0], pp[rA + 1]);
        unsigned pkA1 = pkbf(pp[rA + 2], pp[rA + 3]);
        unsigned pkB0 = pkbf(pp[rA + 4], pp[rA + 5]);
        unsigned pkB1 = pkbf(pp[rA + 6], pp[rA + 7]);
        unsigned u0 = (unsigned)__shfl_xor((int)(hi ? pkA0 : pkB0), 32, 64);
        unsigned u1 = (unsigned)__shfl_xor((int)(hi ? pkA1 : pkB1), 32, 64);
        u32x4v pu;
        pu[0] = hi ? u0 : pkA0;
        pu[1] = hi ? u1 : pkA1;
        pu[2] = hi ? pkB0 : u0;
        pu[3] = hi ? pkB1 : u1;
        short8 pf = __builtin_bit_cast(short8, pu);
        o0 = __builtin_amdgcn_mfma_f32_32x32x16_bf16(va0[ct], pf, o0, 0, 0, 0);
        o1 = __builtin_amdgcn_mfma_f32_32x32x16_bf16(va1[ct], pf, o1, 0, 0, 0);
      }
    }
    __builtin_amdgcn_s_setprio(0);
  }

  const float invl = 1.0f / ell;
  u16* orow = ao + ((size_t)(b * 2048 + q0 + l31)) * 1024 + h * 64;
#pragma unroll
  for (int qd = 0; qd < 4; qd++) {
    us4 st0, st1;
#pragma unroll
    for (int j = 0; j < 4; j++) {
      st0[j] = f2bf(o0[qd * 4 + j] * invl);
      st1[j] = f2bf(o1[qd * 4 + j] * invl);
    }
    *(us4*)(orow + qd * 8 + hi * 4) = st0;
    *(us4*)(orow + 32 + qd * 8 + hi * 4) = st1;
  }
}

// --------------------------- output projection ------------------------------
__global__ __launch_bounds__(256) void gemm_out_kernel(const u16* __restrict__ ab,
                                                       const u16* __restrict__ wo,
                                                       float* __restrict__ out) {
  const int tm = blockIdx.x, tn = blockIdx.y;
  __shared__ __align__(16) u16 As[128 * 32];
  __shared__ __align__(16) u16 Bs[128 * 32];

  const int t = threadIdx.x, lane = t & 63, w = t >> 6;
  const int wm = w >> 1, wn = w & 1, lg = lane >> 4, lr = lane & 15;

  floatx4 acc[4][4];
#pragma unroll
  for (int i = 0; i < 4; i++)
#pragma unroll
    for (int j = 0; j < 4; j++) acc[i][j] = (floatx4){0.f, 0.f, 0.f, 0.f};

  const int rowA = tm * 128, rowB = tn * 128;
  for (int kt = 0; kt < 32; ++kt) {
#pragma unroll
    for (int s = 0; s < 2; s++) {
      int c = t + s * 256;
      int r = c >> 2, kc = c & 3;
      *(uint4v*)(As + r * 32 + kc * 8) =
          *(const uint4v*)(ab + (size_t)(rowA + r) * 1024 + kt * 32 + kc * 8);
      *(uint4v*)(Bs + r * 32 + kc * 8) =
          *(const uint4v*)(wo + (size_t)(rowB + r) * 1024 + kt * 32 + kc * 8);
    }
    __syncthreads();
    short8 af[4], bw[4];
#pragma unroll
    for (int i = 0; i < 4; i++)
      af[i] = *(const short8*)(As + (wm * 64 + i * 16 + lr) * 32 + lg * 8);
#pragma unroll
    for (int j = 0; j < 4; j++)
      bw[j] = *(const short8*)(Bs + (wn * 64 + j * 16 + lr) * 32 + lg * 8);
#pragma unroll
    for (int i = 0; i < 4; i++)
#pragma unroll
      for (int j = 0; j < 4; j++)
        acc[i][j] = __builtin_amdgcn_mfma_f32_16x16x32_bf16(af[i], bw[j], acc[i][j], 0, 0, 0);
    __syncthreads();
  }

  const int rowbase = tm * 128 + wm * 64, colbase = tn * 128 + wn * 64;
#pragma unroll
  for (int i = 0; i < 4; i++)
#pragma unroll
    for (int ii = 0; ii < 4; ii++) {
      int gm = rowbase + i * 16 + lg * 4 + ii;
#pragma unroll
      for (int j = 0; j < 4; j++) {
        int ge = colbase + j * 16 + lr;
        out[(size_t)gm * 1024 + ge] = acc[i][j][ii];
      }
    }
}

// ---------------------------------------------------------------------------
extern "C" void kernel_launch(void* const* d_in, const int* in_sizes, int n_in,
                              void* d_out, int out_size, void* d_ws, size_t ws_size,
                              hipStream_t stream) {
  const float* x     = (const float*)d_in[0];
  const float* Wq    = (const float*)d_in[1];
  const float* Wk    = (const float*)d_in[2];
  const float* Wv    = (const float*)d_in[3];
  const float* Wo    = (const float*)d_in[4];
  const float* alpha = (const float*)d_in[5];
  const float* Tb    = (const float*)d_in[6];
  const float* cw    = (const float*)d_in[7];
  const float* cb    = (const float*)d_in[8];
  const int*   tstep = (const int*)d_in[11];

  char* ws = (char*)d_ws;
  u16* xb  = (u16*)(ws + OFF_XB);
  u16* wqb = (u16*)(ws + OFF_WQ);
  u16* wkb = (u16*)(ws + OFF_WK);
  u16* wvb = (u16*)(ws + OFF_WV);
  u16* wob = (u16*)(ws + OFF_WO);
  u16* qb  = (u16*)(ws + OFF_Q);
  u16* kb  = (u16*)(ws + OFF_K);
  u16* vb  = (u16*)(ws + OFF_V);
  u16* aob = (u16*)(ws + OFF_AO);
  u16* vtb = (u16*)(ws + OFF_XB);           // aliases xb (dead after gemm_qkv)
  float2* rt = (float2*)(ws + OFF_AO);      // rope table; AO region dead until attn
  float* sc = (float*)(ws + OFF_SC);        // [0:2) inv_scale
  float* part = sc + 4;                     // 4096 partials (16KB)

  // fused converts + complexity partials (atomic-free)
  cvt_all_kernel<<<8192, 256, 0, stream>>>(x, Wq, Wk, Wv, Wo, cw,
                                           xb, wqb, wkb, wvb, wob, part);
  // rope table + temperature finalize (merged)
  prep_kernel<<<257, 256, 0, stream>>>(part, cb, alpha, Tb, tstep, sc, rt);

  // QKV projection + RoPE (table-driven)
  gemm_qkv_kernel<<<dim3(32, 8, 3), 256, 0, stream>>>(xb, wqb, wkb, wvb, rt, qb, kb, vb);

  // V -> V^T (into dead xb region)
  vtrans_kernel<<<dim3(32, 32), 256, 0, stream>>>(vb, vtb);

  // causal flash attention (R5 structure + setprio + defer-max)
  attn_kernel<<<dim3(512), 256, 0, stream>>>(qb, kb, vtb, aob, sc);

  // output projection
  gemm_out_kernel<<<dim3(32, 8), 256, 0, stream>>>(aob, wob, (float*)d_out);
}

// Round 10
// 258.776 us; speedup vs baseline: 1.1560x; 1.1560x over previous
//
#include <hip/hip_runtime.h>

// ---------------------------------------------------------------------------
// QalbAttention. B=2, N=2048, D=1024, H=16, HD=64.
// R5: attn 32x32x16 swapped-operand MFMA, lane-local softmax (81us, 116 VGPR).
// R7/R8: split-K attn refuted. Atomic-free cvt partials (non-attn 227->181us).
// R9: setprio+defer-max riders pushed attn to 132 VGPR -> occupancy halved ->
//     115.8us. REFUTED: no register headroom on this body.
// R10: attn = byte-exact R5 body. V-transpose fused into gemm_qkv epilogue
//      (V^T written directly to OFF_V; vtrans kernel deleted).
// ---------------------------------------------------------------------------

typedef short short8 __attribute__((ext_vector_type(8)));      // 8 bf16 (4 VGPR)
typedef float floatx4 __attribute__((ext_vector_type(4)));
typedef float f32x16 __attribute__((ext_vector_type(16)));
typedef unsigned int uint4v __attribute__((ext_vector_type(4)));
typedef unsigned int u32x4v __attribute__((ext_vector_type(4)));
typedef unsigned short us4 __attribute__((ext_vector_type(4)));
typedef unsigned short u16;

#define DEV __device__ __forceinline__

static const int Bb = 2;

// ws layout (bytes)
static const size_t OFF_XB = 0;                       // x bf16 8MB (dead after gemm_qkv)
static const size_t OFF_WQ = 8388608;
static const size_t OFF_WK = OFF_WQ + 2097152;
static const size_t OFF_WV = OFF_WK + 2097152;
static const size_t OFF_WO = OFF_WV + 2097152;
static const size_t OFF_Q  = OFF_WO + 2097152;        // (B,H,N,HD) bf16 8MB
static const size_t OFF_K  = OFF_Q + 8388608;
static const size_t OFF_V  = OFF_K + 8388608;         // V^T [bh][64][2048] bf16 8MB
static const size_t OFF_AO = OFF_V + 8388608;         // attn-out 8MB; rope table BEFORE attn
static const size_t OFF_SC = OFF_AO + 8388608;        // [0:2) inv_scale; +16: 4096 partials

DEV u16 f2bf(float f) {                               // RNE float->bf16
  unsigned int u = __builtin_bit_cast(unsigned int, f);
  u += 0x7fffu + ((u >> 16) & 1u);
  return (u16)(u >> 16);
}

DEV unsigned pkbf(float lo, float hi) {               // pack 2xf32 -> 2xbf16 (RNE)
  unsigned r;
  asm("v_cvt_pk_bf16_f32 %0, %1, %2" : "=v"(r) : "v"(lo), "v"(hi));
  return r;
}

// ---------------- fused fp32->bf16 convert + complexity dot ------------------
// blocks [0,4096): x (+ x.cw partial, atomic-free); [4096,8192): weights.
__global__ __launch_bounds__(256) void cvt_all_kernel(
    const float* __restrict__ x, const float* __restrict__ wq,
    const float* __restrict__ wk, const float* __restrict__ wv,
    const float* __restrict__ wo, const float* __restrict__ cw,
    u16* __restrict__ xb, u16* __restrict__ wqb, u16* __restrict__ wkb,
    u16* __restrict__ wvb, u16* __restrict__ wob, float* __restrict__ part) {
  const int blk = blockIdx.x;
  if (blk < 4096) {
    int i = blk * 256 + threadIdx.x;          // float4 index into x (1048576)
    float4 f = ((const float4*)x)[i];
    us4 o;
    o[0] = f2bf(f.x); o[1] = f2bf(f.y); o[2] = f2bf(f.z); o[3] = f2bf(f.w);
    ((us4*)xb)[i] = o;
    float4 c = ((const float4*)cw)[i & 255];  // D/4 = 256
    float acc = f.x * c.x + f.y * c.y + f.z * c.z + f.w * c.w;
    __shared__ float red[256];
    red[threadIdx.x] = acc;
    __syncthreads();
    for (int s = 128; s > 0; s >>= 1) {
      if (threadIdx.x < s) red[threadIdx.x] += red[threadIdx.x + s];
      __syncthreads();
    }
    if (threadIdx.x == 0) part[blk] = red[0];   // plain store, no atomics
  } else {
    int r = blk - 4096;
    int wi = r >> 10;
    int i = (r & 1023) * 256 + threadIdx.x;   // float4 index (262144)
    const float* src = (wi == 0) ? wq : (wi == 1) ? wk : (wi == 2) ? wv : wo;
    u16* dst = (wi == 0) ? wqb : (wi == 1) ? wkb : (wi == 2) ? wvb : wob;
    float4 f = ((const float4*)src)[i];
    us4 o;
    o[0] = f2bf(f.x); o[1] = f2bf(f.y); o[2] = f2bf(f.z); o[3] = f2bf(f.w);
    ((us4*)dst)[i] = o;
  }
}

// ---------------- prep: rope table (blocks 0..255) + scale finalize (256) ----
__global__ void prep_kernel(const float* __restrict__ part,
                            const float* __restrict__ cb,
                            const float* __restrict__ alpha,
                            const float* __restrict__ tb,
                            const int* __restrict__ tstep,
                            float* __restrict__ out, float2* __restrict__ rt) {
  if (blockIdx.x == 256) {
    const int b = threadIdx.x >> 7, t = threadIdx.x & 127;
    float s = 0.f;
    for (int i = t; i < 2048; i += 128) s += part[b * 2048 + i];
    __shared__ float red[2][128];
    red[b][t] = s;
    __syncthreads();
    for (int st = 64; st > 0; st >>= 1) {
      if (t < st) red[b][t] += red[b][t + st];
      __syncthreads();
    }
    if (t == 0) {
      float sm = red[b][0] * (1.0f / 2048.0f) + cb[0];
      float cx = 1.0f / (1.0f + expf(-sm));
      float Te = (fabsf(tb[0]) + 1.0f) * (0.5f + cx);
      float psi = 1.0f + alpha[0] * sinf(6.283185307179586f * (float)tstep[0] / Te);
      out[b] = 1.0f / (8.0f * psi);
    }
  } else {
    int i = blockIdx.x * 256 + threadIdx.x;   // 65536
    int pos = i >> 5, hd2 = i & 31;
    float ang = (float)pos * exp2f(-(float)hd2 * 0.41524101186092030f);
    float sv, cv;
    sincosf(ang, &sv, &cv);
    rt[i] = make_float2(cv, sv);
  }
}

// --------------------------- QKV GEMM + RoPE + V^T --------------------------
// C[m,e] = sum_k A[m,k]*W[e,k]; 128x128 tile, BK=32, 4 waves 2x2, 4x4 frags.
// which==2 (V) writes V^T [bh][hd][pos] directly: the 4 ii-values of a frag
// are 4 consecutive pos -> one us4 (8B) store per (i,j).
__global__ __launch_bounds__(256) void gemm_qkv_kernel(
    const u16* __restrict__ xb, const u16* __restrict__ wq, const u16* __restrict__ wk,
    const u16* __restrict__ wv, const float2* __restrict__ rt,
    u16* __restrict__ q, u16* __restrict__ k, u16* __restrict__ vt) {
  const int tm = blockIdx.x, tn = blockIdx.y, which = blockIdx.z;
  const u16* W = (which == 0) ? wq : (which == 1) ? wk : wv;

  __shared__ __align__(16) u16 As[128 * 32];
  __shared__ __align__(16) u16 Bs[128 * 32];

  const int t = threadIdx.x, lane = t & 63, w = t >> 6;
  const int wm = w >> 1, wn = w & 1, lg = lane >> 4, lr = lane & 15;

  floatx4 acc[4][4];
#pragma unroll
  for (int i = 0; i < 4; i++)
#pragma unroll
    for (int j = 0; j < 4; j++) acc[i][j] = (floatx4){0.f, 0.f, 0.f, 0.f};

  const int rowA = tm * 128, rowB = tn * 128;
  for (int kt = 0; kt < 32; ++kt) {
#pragma unroll
    for (int s = 0; s < 2; s++) {
      int c = t + s * 256;
      int r = c >> 2, kc = c & 3;
      *(uint4v*)(As + r * 32 + kc * 8) =
          *(const uint4v*)(xb + (size_t)(rowA + r) * 1024 + kt * 32 + kc * 8);
      *(uint4v*)(Bs + r * 32 + kc * 8) =
          *(const uint4v*)(W + (size_t)(rowB + r) * 1024 + kt * 32 + kc * 8);
    }
    __syncthreads();
    short8 af[4], bw[4];
#pragma unroll
    for (int i = 0; i < 4; i++)
      af[i] = *(const short8*)(As + (wm * 64 + i * 16 + lr) * 32 + lg * 8);
#pragma unroll
    for (int j = 0; j < 4; j++)
      bw[j] = *(const short8*)(Bs + (wn * 64 + j * 16 + lr) * 32 + lg * 8);
#pragma unroll
    for (int i = 0; i < 4; i++)
#pragma unroll
      for (int j = 0; j < 4; j++)
        acc[i][j] = __builtin_amdgcn_mfma_f32_16x16x32_bf16(af[i], bw[j], acc[i][j], 0, 0, 0);
    __syncthreads();
  }

  const int rowbase = tm * 128 + wm * 64, colbase = tn * 128 + wn * 64;
  if (which <= 1) {
    u16* dst = (which == 0) ? q : k;
#pragma unroll
    for (int i = 0; i < 4; i++)
#pragma unroll
      for (int ii = 0; ii < 4; ii++) {
        int gm = rowbase + i * 16 + lg * 4 + ii;
        int pos = gm & 2047, bb = gm >> 11;
#pragma unroll
        for (int jp = 0; jp < 2; jp++) {
          int hd2 = jp * 16 + lr;
          float2 cs = rt[pos * 32 + hd2];
          float a0 = acc[i][jp][ii], a1 = acc[i][jp + 2][ii];
          int e0 = colbase + jp * 16 + lr;
          int hh = e0 >> 6;
          size_t base = (((size_t)bb * 16 + hh) * 2048 + pos) * 64;
          dst[base + hd2]      = f2bf(a0 * cs.x - a1 * cs.y);
          dst[base + hd2 + 32] = f2bf(a1 * cs.x + a0 * cs.y);
        }
      }
  } else {
    // V^T epilogue: vt[(b*16+h)*131072 + hd*2048 + pos], 4 consecutive pos.
#pragma unroll
    for (int i = 0; i < 4; i++) {
      int gm0 = rowbase + i * 16 + lg * 4;        // 4-aligned; no 2048 crossing
      int pos0 = gm0 & 2047, bb = gm0 >> 11;
#pragma unroll
      for (int j = 0; j < 4; j++) {
        int ge = colbase + j * 16 + lr;
        int hh = ge >> 6, hd = ge & 63;
        us4 st;
#pragma unroll
        for (int ii = 0; ii < 4; ii++) st[ii] = f2bf(acc[i][j][ii]);
        *(us4*)(vt + ((size_t)(bb * 16 + hh)) * 131072 + (size_t)hd * 2048 + pos0) = st;
      }
    }
  }
}

// --------------------------- flash attention (R5 exact) ---------------------
// 512 blocks x 4 waves; wave owns a 32-row q-tile (tiles {p,31-p,32+p,63-p}
// per block -> constant block work). S^T = mfma32x32(K,Q): lane&31 = q-row,
// softmax lane-local; P packed to PV B-frags via cvt_pk + shfl_xor(32);
// O^T = mfma32x32(V^T, P). No LDS, no barriers.
__global__ __launch_bounds__(256) void attn_kernel(
    const u16* __restrict__ q, const u16* __restrict__ k, const u16* __restrict__ vt,
    u16* __restrict__ ao, const float* __restrict__ scale_ws) {
  const int bid = blockIdx.x;
  const int swz = (bid & 7) * 64 + (bid >> 3);    // XCD x -> bh in [4x,4x+4)
  const int bh = swz >> 4, p = swz & 15;
  const int b = bh >> 4, h = bh & 15;
  const int w = threadIdx.x >> 6, lane = threadIdx.x & 63;
  const int l31 = lane & 31, hi = lane >> 5;
  const int tsel = (w == 0) ? p : (w == 1) ? 31 - p : (w == 2) ? 32 + p : 63 - p;
  const int q0 = tsel * 32;
  const int KT = tsel >> 1;                        // last 64-col k-tile index
  const float isc2 = scale_ws[b] * 1.4426950408889634f;   // fold log2e
  const size_t koff = (size_t)bh * 131072;
  const float NINF = -__builtin_inff();

  // Q B-frags (col = q = l31, k = k4*16 + hi*8 + e), hoisted
  short8 bq[4];
#pragma unroll
  for (int k4 = 0; k4 < 4; k4++)
    bq[k4] = *(const short8*)(q + koff + (size_t)(q0 + l31) * 64 + k4 * 16 + hi * 8);

  f32x16 o0, o1;
#pragma unroll
  for (int r = 0; r < 16; r++) { o0[r] = 0.f; o1[r] = 0.f; }
  float m2 = NINF, ell = 0.f;

  for (int kt = 0; kt <= KT; ++kt) {
    const int cbase = kt << 6;
    const bool haveMt1 = (cbase + 32 <= q0 + 31);  // false only on even-tile diag

    // ---- issue K fragment loads (A-op: row = c, k = k4*16+hi*8+e) ----
    short8 ka0[4], ka1[4];
#pragma unroll
    for (int k4 = 0; k4 < 4; k4++)
      ka0[k4] = *(const short8*)(k + koff + (size_t)(cbase + l31) * 64 + k4 * 16 + hi * 8);
    if (haveMt1) {
#pragma unroll
      for (int k4 = 0; k4 < 4; k4++)
        ka1[k4] = *(const short8*)(k + koff + (size_t)(cbase + 32 + l31) * 64 + k4 * 16 + hi * 8);
    }
    // ---- issue V^T fragment loads early (A-op for PV: row=d, k=c) ----
    const int nct = haveMt1 ? 4 : 2;
    short8 va0[4], va1[4];
#pragma unroll
    for (int ct = 0; ct < 4; ct++) {
      if (ct < nct) {
        va0[ct] = *(const short8*)(vt + koff + (size_t)l31 * 2048 + cbase + ct * 16 + hi * 8);
        va1[ct] = *(const short8*)(vt + koff + (size_t)(32 + l31) * 2048 + cbase + ct * 16 + hi * 8);
      }
    }

    // ---- S^T = K · Q  (D col = q = l31, row = c-offset crow) ----
    f32x16 s0, s1;
#pragma unroll
    for (int r = 0; r < 16; r++) { s0[r] = 0.f; s1[r] = 0.f; }
#pragma unroll
    for (int k4 = 0; k4 < 4; k4++)
      s0 = __builtin_amdgcn_mfma_f32_32x32x16_bf16(ka0[k4], bq[k4], s0, 0, 0, 0);
    if (haveMt1) {
#pragma unroll
      for (int k4 = 0; k4 < 4; k4++)
        s1 = __builtin_amdgcn_mfma_f32_32x32x16_bf16(ka1[k4], bq[k4], s1, 0, 0, 0);
    }

    // scale to log2 domain; causal mask on the diagonal tile
#pragma unroll
    for (int r = 0; r < 16; r++) { s0[r] *= isc2; s1[r] *= isc2; }
    if (kt == KT) {
      const int thr = q0 + l31 - cbase;
#pragma unroll
      for (int r = 0; r < 16; r++) {
        const int crow = (r & 3) + 8 * (r >> 2) + 4 * hi;
        if (crow > thr) s0[r] = NINF;
        if (crow + 32 > thr) s1[r] = NINF;       // also kills unused s1 when !haveMt1
      }
    }

    // ---- online softmax: lane-local + one cross-half shuffle ----
    float mx = s0[0];
#pragma unroll
    for (int r = 1; r < 16; r++) mx = fmaxf(mx, s0[r]);
#pragma unroll
    for (int r = 0; r < 16; r++) mx = fmaxf(mx, s1[r]);
    mx = fmaxf(mx, __shfl_xor(mx, 32, 64));
    const float mn = fmaxf(m2, mx);
    const float rsc = exp2f(m2 - mn);
    m2 = mn;
    f32x16 p0, p1;
    float ps = 0.f;
#pragma unroll
    for (int r = 0; r < 16; r++) { p0[r] = exp2f(s0[r] - mn); ps += p0[r]; }
#pragma unroll
    for (int r = 0; r < 16; r++) { p1[r] = exp2f(s1[r] - mn); ps += p1[r]; }
    ps += __shfl_xor(ps, 32, 64);
    ell = ell * rsc + ps;
#pragma unroll
    for (int r = 0; r < 16; r++) { o0[r] *= rsc; o1[r] *= rsc; }

    // ---- pack P -> B-frags (cvt_pk + cross-half exchange) and PV ----
#pragma unroll
    for (int ct = 0; ct < 4; ct++) {
      if (ct < nct) {
        const f32x16& pp = (ct < 2) ? p0 : p1;
        const int rA = (ct & 1) * 8;
        unsigned pkA0 = pkbf(pp[rA + 0], pp[rA + 1]);
        unsigned pkA1 = pkbf(pp[rA + 2], pp[rA + 3]);
        unsigned pkB0 = pkbf(pp[rA + 4], pp[rA + 5]);
        unsigned pkB1 = pkbf(pp[rA + 6], pp[rA + 7]);
        unsigned u0 = (unsigned)__shfl_xor((int)(hi ? pkA0 : pkB0), 32, 64);
        unsigned u1 = (unsigned)__shfl_xor((int)(hi ? pkA1 : pkB1), 32, 64);
        u32x4v pu;
        pu[0] = hi ? u0 : pkA0;
        pu[1] = hi ? u1 : pkA1;
        pu[2] = hi ? pkB0 : u0;
        pu[3] = hi ? pkB1 : u1;
        short8 pf = __builtin_bit_cast(short8, pu);
        o0 = __builtin_amdgcn_mfma_f32_32x32x16_bf16(va0[ct], pf, o0, 0, 0, 0);
        o1 = __builtin_amdgcn_mfma_f32_32x32x16_bf16(va1[ct], pf, o1, 0, 0, 0);
      }
    }
  }

  // ---- epilogue: O^T -> ao[q][h*64+d]; 4 consecutive d per reg-quad ----
  const float invl = 1.0f / ell;
  u16* orow = ao + ((size_t)(b * 2048 + q0 + l31)) * 1024 + h * 64;
#pragma unroll
  for (int qd = 0; qd < 4; qd++) {
    us4 st0, st1;
#pragma unroll
    for (int j = 0; j < 4; j++) {
      st0[j] = f2bf(o0[qd * 4 + j] * invl);
      st1[j] = f2bf(o1[qd * 4 + j] * invl);
    }
    *(us4*)(orow + qd * 8 + hi * 4) = st0;          // d = 8qd+4hi+j
    *(us4*)(orow + 32 + qd * 8 + hi * 4) = st1;     // d = 32+8qd+4hi+j
  }
}

// --------------------------- output projection ------------------------------
__global__ __launch_bounds__(256) void gemm_out_kernel(const u16* __restrict__ ab,
                                                       const u16* __restrict__ wo,
                                                       float* __restrict__ out) {
  const int tm = blockIdx.x, tn = blockIdx.y;
  __shared__ __align__(16) u16 As[128 * 32];
  __shared__ __align__(16) u16 Bs[128 * 32];

  const int t = threadIdx.x, lane = t & 63, w = t >> 6;
  const int wm = w >> 1, wn = w & 1, lg = lane >> 4, lr = lane & 15;

  floatx4 acc[4][4];
#pragma unroll
  for (int i = 0; i < 4; i++)
#pragma unroll
    for (int j = 0; j < 4; j++) acc[i][j] = (floatx4){0.f, 0.f, 0.f, 0.f};

  const int rowA = tm * 128, rowB = tn * 128;
  for (int kt = 0; kt < 32; ++kt) {
#pragma unroll
    for (int s = 0; s < 2; s++) {
      int c = t + s * 256;
      int r = c >> 2, kc = c & 3;
      *(uint4v*)(As + r * 32 + kc * 8) =
          *(const uint4v*)(ab + (size_t)(rowA + r) * 1024 + kt * 32 + kc * 8);
      *(uint4v*)(Bs + r * 32 + kc * 8) =
          *(const uint4v*)(wo + (size_t)(rowB + r) * 1024 + kt * 32 + kc * 8);
    }
    __syncthreads();
    short8 af[4], bw[4];
#pragma unroll
    for (int i = 0; i < 4; i++)
      af[i] = *(const short8*)(As + (wm * 64 + i * 16 + lr) * 32 + lg * 8);
#pragma unroll
    for (int j = 0; j < 4; j++)
      bw[j] = *(const short8*)(Bs + (wn * 64 + j * 16 + lr) * 32 + lg * 8);
#pragma unroll
    for (int i = 0; i < 4; i++)
#pragma unroll
      for (int j = 0; j < 4; j++)
        acc[i][j] = __builtin_amdgcn_mfma_f32_16x16x32_bf16(af[i], bw[j], acc[i][j], 0, 0, 0);
    __syncthreads();
  }

  const int rowbase = tm * 128 + wm * 64, colbase = tn * 128 + wn * 64;
#pragma unroll
  for (int i = 0; i < 4; i++)
#pragma unroll
    for (int ii = 0; ii < 4; ii++) {
      int gm = rowbase + i * 16 + lg * 4 + ii;
#pragma unroll
      for (int j = 0; j < 4; j++) {
        int ge = colbase + j * 16 + lr;
        out[(size_t)gm * 1024 + ge] = acc[i][j][ii];
      }
    }
}

// ---------------------------------------------------------------------------
extern "C" void kernel_launch(void* const* d_in, const int* in_sizes, int n_in,
                              void* d_out, int out_size, void* d_ws, size_t ws_size,
                              hipStream_t stream) {
  const float* x     = (const float*)d_in[0];
  const float* Wq    = (const float*)d_in[1];
  const float* Wk    = (const float*)d_in[2];
  const float* Wv    = (const float*)d_in[3];
  const float* Wo    = (const float*)d_in[4];
  const float* alpha = (const float*)d_in[5];
  const float* Tb    = (const float*)d_in[6];
  const float* cw    = (const float*)d_in[7];
  const float* cb    = (const float*)d_in[8];
  const int*   tstep = (const int*)d_in[11];

  char* ws = (char*)d_ws;
  u16* xb  = (u16*)(ws + OFF_XB);
  u16* wqb = (u16*)(ws + OFF_WQ);
  u16* wkb = (u16*)(ws + OFF_WK);
  u16* wvb = (u16*)(ws + OFF_WV);
  u16* wob = (u16*)(ws + OFF_WO);
  u16* qb  = (u16*)(ws + OFF_Q);
  u16* kb  = (u16*)(ws + OFF_K);
  u16* vtb = (u16*)(ws + OFF_V);            // V^T written directly by gemm_qkv
  u16* aob = (u16*)(ws + OFF_AO);
  float2* rt = (float2*)(ws + OFF_AO);      // rope table; AO region dead until attn
  float* sc = (float*)(ws + OFF_SC);        // [0:2) inv_scale
  float* part = sc + 4;                     // 4096 partials (16KB)

  // fused converts + complexity partials (atomic-free)
  cvt_all_kernel<<<8192, 256, 0, stream>>>(x, Wq, Wk, Wv, Wo, cw,
                                           xb, wqb, wkb, wvb, wob, part);
  // rope table + temperature finalize (merged)
  prep_kernel<<<257, 256, 0, stream>>>(part, cb, alpha, Tb, tstep, sc, rt);

  // QKV projection + RoPE + direct V^T
  gemm_qkv_kernel<<<dim3(32, 8, 3), 256, 0, stream>>>(xb, wqb, wkb, wvb, rt, qb, kb, vtb);

  // causal flash attention (R5 exact)
  attn_kernel<<<dim3(512), 256, 0, stream>>>(qb, kb, vtb, aob, sc);

  // output projection
  gemm_out_kernel<<<dim3(32, 8), 256, 0, stream>>>(aob, wob, (float*)d_out);
}